// Round 8
// baseline (88.884 us; speedup 1.0000x reference)
//
#include <hip/hip_runtime.h>

// Problem: B=2, T=2048, C=1024, H=16, D=64
// qkv = x @ w + b ; q,k,v split; att = relu(causal(q k^T / 8)); y = att @ v
// Output fp32 [B,T,C]. Compute in bf16 MFMA with fp32 accum.

typedef unsigned int u32;
typedef float  f32x4  __attribute__((ext_vector_type(4)));
typedef float  f32x16 __attribute__((ext_vector_type(16)));
typedef short  s16x8  __attribute__((ext_vector_type(8)));
typedef short  s16x4  __attribute__((ext_vector_type(4)));

#define MFMA_BF16(a, b, c) __builtin_amdgcn_mfma_f32_16x16x32_bf16((a), (b), (c), 0, 0, 0)
#define MFMA32(a, b, c)    __builtin_amdgcn_mfma_f32_32x32x16_bf16((a), (b), (c), 0, 0, 0)
#define LO4(v) __builtin_shufflevector((v), (v), 0, 1, 2, 3)
#define HI4(v) __builtin_shufflevector((v), (v), 4, 5, 6, 7)

#define GLOAD16(g, l)                                                        \
  __builtin_amdgcn_global_load_lds(                                          \
      (__attribute__((address_space(1))) void*)(g),                          \
      (__attribute__((address_space(3))) void*)(l), 16, 0, 0)

__device__ __forceinline__ unsigned short f2bf(float f) {
  union { float f; u32 u; } x; x.f = f;
  u32 r = (x.u + 0x7fffu + ((x.u >> 16) & 1u)) >> 16;
  return (unsigned short)r;
}

static __device__ __forceinline__ u32 cvtpk1(float a, float b) {
  u32 r;
  asm("v_cvt_pk_bf16_f32 %0, %1, %2" : "=v"(r) : "v"(a), "v"(b));
  return r;
}
static __device__ __forceinline__ void pl32swap(u32& a, u32& b) {
  asm("v_permlane32_swap_b32 %0, %1" : "+v"(a), "+v"(b));
}

// ---------------- kernel 1: x fp32 -> bf16 ----------------
__global__ void cvt_x_kernel(const float* __restrict__ x, unsigned short* __restrict__ xb) {
  int i = blockIdx.x * 256 + threadIdx.x;
  float4 v = ((const float4*)x)[i];
  ushort4 o;
  o.x = f2bf(v.x); o.y = f2bf(v.y); o.z = f2bf(v.z); o.w = f2bf(v.w);
  ((ushort4*)xb)[i] = o;
}

// ---------------- kernel 2: w [1024][3072] fp32 -> wT [3072][1024] bf16 ----
__global__ void transpose_w_kernel(const float* __restrict__ w, unsigned short* __restrict__ wT) {
  __shared__ unsigned short TL[64][72];
  const int tid = threadIdx.x;
  const int c0 = blockIdx.x * 64;
  const int r0 = blockIdx.y * 64;
#pragma unroll
  for (int p = 0; p < 4; ++p) {
    int r = p * 16 + (tid >> 4);
    int c = (tid & 15) * 4;
    float4 v = *(const float4*)&w[(size_t)(r0 + r) * 3072 + c0 + c];
    TL[c + 0][r] = f2bf(v.x);
    TL[c + 1][r] = f2bf(v.y);
    TL[c + 2][r] = f2bf(v.z);
    TL[c + 3][r] = f2bf(v.w);
  }
  __syncthreads();
#pragma unroll
  for (int p = 0; p < 4; ++p) {
    int c = p * 16 + (tid >> 4);
    int r = (tid & 15) * 4;
    ushort4 o;
    o.x = TL[c][r + 0]; o.y = TL[c][r + 1]; o.z = TL[c][r + 2]; o.w = TL[c][r + 3];
    *(ushort4*)&wT[(size_t)(c0 + c) * 1024 + r0 + r] = o;
  }
}

// ---------------- kernel 3: GEMM qkv = xb @ wT^T + bias ------------------
// bn<8: q (1/8-scaled) -> Qrm [4096][1024]; bn in [8,16): k -> Krm [4096][1024];
// bn>=16: v -> Vf frag-order: frag(bh,c,sb,dh) 1KB contiguous, elem
// (hiL*32+li)*8+e = V[s=c*32+sb*16+hiL*8+e][d=dh*32+li].
__global__ __launch_bounds__(256, 3) void gemm_qkv_kernel(
    const unsigned short* __restrict__ A, const unsigned short* __restrict__ Bt,
    const float* __restrict__ bias, unsigned short* __restrict__ Qrm,
    unsigned short* __restrict__ Krm, unsigned short* __restrict__ Vf) {
  __shared__ __align__(16) unsigned short SM[8448];   // As | Bs, reused as TL
  unsigned short* As = SM;
  unsigned short* Bs = SM + 4096;
  const int tid = threadIdx.x;
  const int lane = tid & 63, wid = tid >> 6;
  const int wr = wid >> 1, wc = wid & 1;
  const int g = lane >> 4, lm = lane & 15;
  const int bid = blockIdx.x;
  const int xcd = bid & 7, wl = bid >> 3;              // wl 0..95
  const int bn = wl % 24;
  const int bm = xcd * 4 + wl / 24;

  const unsigned short* gA = A  + (size_t)(bm * 128 + wid * 32 + (lane >> 2)) * 1024 + (lane & 3) * 8;
  const unsigned short* gB = Bt + (size_t)(bn * 128 + wid * 32 + (lane >> 2)) * 1024 + (lane & 3) * 8;
  unsigned short* lA0 = &As[wid * 1024];
  unsigned short* lA1 = &As[wid * 1024 + 512];
  unsigned short* lB0 = &Bs[wid * 1024];
  unsigned short* lB1 = &Bs[wid * 1024 + 512];

  f32x4 acc[4][4] = {};

  for (int kt = 0; kt < 32; ++kt) {
    __syncthreads();
    const unsigned short* a0 = gA + kt * 32;
    const unsigned short* b0 = gB + kt * 32;
    GLOAD16(a0,             lA0);
    GLOAD16(a0 + 16 * 1024, lA1);
    GLOAD16(b0,             lB0);
    GLOAD16(b0 + 16 * 1024, lB1);
    __syncthreads();

    s16x8 af[4], bf[4];
#pragma unroll
    for (int m = 0; m < 4; ++m)
      af[m] = *(const s16x8*)&As[(wr * 64 + m * 16 + lm) * 32 + g * 8];
#pragma unroll
    for (int n = 0; n < 4; ++n)
      bf[n] = *(const s16x8*)&Bs[(wc * 64 + n * 16 + lm) * 32 + g * 8];
#pragma unroll
    for (int m = 0; m < 4; ++m)
#pragma unroll
      for (int n = 0; n < 4; ++n)
        acc[m][n] = MFMA_BF16(af[m], bf[n], acc[m][n]);
  }

  if (bn < 8) {                                  // q, pre-scaled by 1/8
#pragma unroll
    for (int m = 0; m < 4; ++m) {
      const int row = bm * 128 + wr * 64 + m * 16 + g * 4;
#pragma unroll
      for (int n = 0; n < 4; ++n) {
        const int col = bn * 128 + wc * 64 + n * 16 + lm;
        const float bv = bias[col];
#pragma unroll
        for (int r = 0; r < 4; ++r)
          Qrm[(size_t)(row + r) * 1024 + col] = f2bf((acc[m][n][r] + bv) * 0.125f);
      }
    }
  } else if (bn < 16) {                          // k, row-major
#pragma unroll
    for (int m = 0; m < 4; ++m) {
      const int row = bm * 128 + wr * 64 + m * 16 + g * 4;
#pragma unroll
      for (int n = 0; n < 4; ++n) {
        const int col = bn * 128 + wc * 64 + n * 16 + lm;     // 1024..2047
        const float bv = bias[col];
#pragma unroll
        for (int r = 0; r < 4; ++r)
          Krm[(size_t)(row + r) * 1024 + (col - 1024)] = f2bf(acc[m][n][r] + bv);
      }
    }
  } else {                                       // v -> Vf frag-order via LDS
    unsigned short* TL = SM;                     // [64 d][132 t-pad]
    const int bb = bm >> 4, bmt = bm & 15;       // b, t-block
    __syncthreads();                             // As/Bs reads done
#pragma unroll
    for (int p = 0; p < 2; ++p) {
      const int h = (bn - 16) * 2 + p;           // this pass's head
      const size_t fb = (size_t)(bb * 16 + h) * 64 * 4;   // frag base
      if (wc == p) {
#pragma unroll
        for (int m = 0; m < 4; ++m) {
          const int r = wr * 64 + m * 16 + g * 4;
#pragma unroll
          for (int n = 0; n < 4; ++n) {
            const int c = n * 16 + lm;           // d 0..63
            const float bv = bias[2048 + h * 64 + c];
            ushort4 o;
#pragma unroll
            for (int r2 = 0; r2 < 4; ++r2)
              ((unsigned short*)&o)[r2] = f2bf(acc[m][n][r2] + bv);
            *(ushort4*)&TL[c * 132 + r] = o;
          }
        }
      }
      __syncthreads();
      const int li = tid & 31, grp = tid >> 5;
      const int dh = grp & 1, oct8 = grp >> 1;
      const int cl = dh * 32 + li;               // d
#pragma unroll
      for (int k2 = 0; k2 < 4; ++k2) {
        const int oct = oct8 * 4 + k2;           // t-octet 0..15
        const int c = bmt * 4 + (oct >> 2);
        const int sb = (oct >> 1) & 1, hiL2 = oct & 1;
        union { s16x8 v; s16x4 hv[2]; } o;
        o.hv[0] = *(const s16x4*)&TL[cl * 132 + oct * 8];
        o.hv[1] = *(const s16x4*)&TL[cl * 132 + oct * 8 + 4];
        *(s16x8*)&Vf[(fb + (size_t)c * 4 + sb * 2 + dh) * 512 + (hiL2 * 32 + li) * 8] = o.v;
      }
      __syncthreads();
    }
  }
}

// ---------------- kernel 4: K row-major -> Kf frag-order ------------------
// frag(bh,c,m) 1KB contiguous, elem (hiL*32+li)*8+e = K[s=c*32+li][d=m*16+hiL*8+e]
__global__ __launch_bounds__(256) void krelayout_kernel(
    const unsigned short* __restrict__ Krm, unsigned short* __restrict__ Kf) {
  __shared__ unsigned short TL[64 * 68];         // [s 0..63][d 0..63 +4]
  const int tid = threadIdx.x;
  const int cg = blockIdx.x;                     // 0..31 (64 s rows)
  const int bh = blockIdx.y;                     // 0..31
  const int b = bh >> 4, h = bh & 15;
  const int s_loc = tid >> 2, pq = tid & 3;
  const unsigned short* src = &Krm[(size_t)(b * 2048 + cg * 64 + s_loc) * 1024 + h * 64];
  s16x8 u0 = *(const s16x8*)&src[pq * 8];
  s16x8 u1 = *(const s16x8*)&src[(pq + 4) * 8];
  unsigned short* t0 = &TL[s_loc * 68 + pq * 8];
  *(s16x4*)(t0)            = LO4(u0);
  *(s16x4*)(t0 + 4)        = HI4(u0);
  *(s16x4*)(t0 + 32)       = LO4(u1);
  *(s16x4*)(t0 + 36)       = HI4(u1);
  __syncthreads();
  const int l = tid & 63, fi = tid >> 6;
  const int hiL = l >> 5, li = l & 31;
#pragma unroll
  for (int ff = 0; ff < 2; ++ff) {
    const int fr = ff * 4 + fi;                  // 0..7
    const int c_loc = fr >> 2, m = fr & 3;
    const unsigned short* tp = &TL[(c_loc * 32 + li) * 68 + m * 16 + hiL * 8];
    union { s16x8 v; s16x4 hv[2]; } o;
    o.hv[0] = *(const s16x4*)(tp);
    o.hv[1] = *(const s16x4*)(tp + 4);
    *(s16x8*)&Kf[(((size_t)bh * 64 + cg * 2 + c_loc) * 4 + m) * 512 + l * 8] = o.v;
  }
}

// ---------------- kernel 5: attention v8 (barrier-free, global-direct) ----
// 2048 blocks x 64 thr; block = one 32-row q-tile, streams K/V frags from
// L2 (frag-order: every load = contiguous 1KB/wave). LPT order (big tiles
// first), XCD-pinned (4 bh/XCD, 1.5MB working set in L2). No LDS/barriers.
__global__ __launch_bounds__(64) void attn_kernel(
    const unsigned short* __restrict__ Qrm, const unsigned short* __restrict__ Kf,
    const unsigned short* __restrict__ Vf, float* __restrict__ out) {
  const int lane = threadIdx.x;
  const int hiL = lane >> 5, li = lane & 31;
  const int bid = blockIdx.x;
  const int xcd = bid & 7, rest = bid >> 3;
  const int bh = xcd * 4 + (rest & 3);
  const int t = 63 - (rest >> 2);                // big tiles dispatched first
  const int b = bh >> 4, h = bh & 15;
  const int qrow0 = t * 32;
  const int qg = qrow0 + li;

  const unsigned short* qp = &Qrm[(size_t)(b * 2048 + qrow0 + li) * 1024 + h * 64 + hiL * 8];
  const s16x8 qf0 = *(const s16x8*)(qp);
  const s16x8 qf1 = *(const s16x8*)(qp + 16);
  const s16x8 qf2 = *(const s16x8*)(qp + 32);
  const s16x8 qf3 = *(const s16x8*)(qp + 48);

  const s16x8* pK = (const s16x8*)(Kf + (size_t)bh * 64 * 2048) + lane;
  const s16x8* pV = (const s16x8*)(Vf + (size_t)bh * 64 * 2048) + lane;

  f32x16 y0 = {}, y1 = {};

#define CHUNK(cc, K0, K1, K2, K3, V0, V1, V2, V3, LAST)                      \
  do {                                                                       \
    __builtin_amdgcn_s_setprio(1);                                           \
    f32x16 sacc = {};                                                        \
    sacc = MFMA32(K0, qf0, sacc);                                            \
    sacc = MFMA32(K1, qf1, sacc);                                            \
    sacc = MFMA32(K2, qf2, sacc);                                            \
    sacc = MFMA32(K3, qf3, sacc);                                            \
    float pr[16];                                                            \
    _Pragma("unroll")                                                        \
    for (int r = 0; r < 16; ++r) {                                           \
      float v = sacc[r] > 0.f ? sacc[r] : 0.f;                               \
      if (LAST) {                                                            \
        const int sg = (cc) * 32 + (r & 3) + 8 * (r >> 2) + 4 * hiL;         \
        if (sg > qg) v = 0.f;                                                \
      }                                                                      \
      pr[r] = v;                                                             \
    }                                                                        \
    _Pragma("unroll")                                                        \
    for (int hh = 0; hh < 2; ++hh) {                                         \
      u32 a0 = cvtpk1(pr[8 * hh + 0], pr[8 * hh + 1]);                       \
      u32 b0 = cvtpk1(pr[8 * hh + 4], pr[8 * hh + 5]);                       \
      u32 a1 = cvtpk1(pr[8 * hh + 2], pr[8 * hh + 3]);                       \
      u32 b1 = cvtpk1(pr[8 * hh + 6], pr[8 * hh + 7]);                       \
      pl32swap(a0, b0);                                                      \
      pl32swap(a1, b1);                                                      \
      union { s16x8 v; u32 w[4]; } pa;                                       \
      pa.w[0] = a0; pa.w[1] = a1; pa.w[2] = b0; pa.w[3] = b1;                \
      if (hh == 0) { y0 = MFMA32(pa.v, V0, y0); y1 = MFMA32(pa.v, V1, y1); } \
      else         { y0 = MFMA32(pa.v, V2, y0); y1 = MFMA32(pa.v, V3, y1); } \
    }                                                                        \
    __builtin_amdgcn_s_setprio(0);                                           \
  } while (0)

  // register double-buffer: named A/B sets (static indexing)
  s16x8 kA0 = pK[0], kA1 = pK[64], kA2 = pK[128], kA3 = pK[192];
  s16x8 vA0 = pV[0], vA1 = pV[64], vA2 = pV[128], vA3 = pV[192];
  s16x8 kB0, kB1, kB2, kB3, vB0, vB1, vB2, vB3;

  int c = 0;
  while (true) {
    const bool lastA = (c == t);
    if (!lastA) {
      const s16x8* kn = pK + (c + 1) * 256;
      const s16x8* vn = pV + (c + 1) * 256;
      kB0 = kn[0]; kB1 = kn[64]; kB2 = kn[128]; kB3 = kn[192];
      vB0 = vn[0]; vB1 = vn[64]; vB2 = vn[128]; vB3 = vn[192];
    }
    CHUNK(c, kA0, kA1, kA2, kA3, vA0, vA1, vA2, vA3, lastA);
    if (lastA) break;
    ++c;
    const bool lastB = (c == t);
    if (!lastB) {
      const s16x8* kn = pK + (c + 1) * 256;
      const s16x8* vn = pV + (c + 1) * 256;
      kA0 = kn[0]; kA1 = kn[64]; kA2 = kn[128]; kA3 = kn[192];
      vA0 = vn[0]; vA1 = vn[64]; vA2 = vn[128]; vA3 = vn[192];
    }
    CHUNK(c, kB0, kB1, kB2, kB3, vB0, vB1, vB2, vB3, lastB);
    if (lastB) break;
    ++c;
  }
#undef CHUNK

  const size_t ob = (size_t)(b * 2048 + qrow0) * 1024 + h * 64 + li;
#pragma unroll
  for (int r = 0; r < 16; ++r) {
    const int ql = (r & 3) + 8 * (r >> 2) + 4 * hiL;
    out[ob + (size_t)ql * 1024]      = y0[r];
    out[ob + (size_t)ql * 1024 + 32] = y1[r];
  }
}

extern "C" void kernel_launch(void* const* d_in, const int* in_sizes, int n_in,
                              void* d_out, int out_size, void* d_ws, size_t ws_size,
                              hipStream_t stream) {
  const float* x    = (const float*)d_in[0];
  const float* w    = (const float*)d_in[1];
  const float* bias = (const float*)d_in[2];
  float* out = (float*)d_out;

  unsigned short* xb  = (unsigned short*)d_ws;            // 4096*1024
  unsigned short* wT  = xb  + (size_t)4096 * 1024;        // 3072*1024
  unsigned short* Qrm = wT  + (size_t)3072 * 1024;        // 4096*1024
  unsigned short* Krm = Qrm + (size_t)4096 * 1024;        // 4096*1024
  unsigned short* Kf  = Krm + (size_t)4096 * 1024;        // 4096*1024
  unsigned short* Vf  = Kf  + (size_t)4096 * 1024;        // 4096*1024

  cvt_x_kernel<<<4096, 256, 0, stream>>>(x, xb);
  transpose_w_kernel<<<dim3(48, 16), 256, 0, stream>>>(w, wT);
  gemm_qkv_kernel<<<768, 256, 0, stream>>>(xb, wT, bias, Qrm, Krm, Vf);
  krelayout_kernel<<<dim3(32, 32), 256, 0, stream>>>(Krm, Kf);
  attn_kernel<<<2048, 64, 0, stream>>>(Qrm, Kf, Vf, out);
}

// Round 9
// 83.514 us; speedup vs baseline: 1.0643x; 1.0643x over previous
//
#include <hip/hip_runtime.h>

// Problem: B=2, T=2048, C=1024, H=16, D=64
// qkv = x @ w + b ; q,k,v split; att = relu(causal(q k^T / 8)); y = att @ v
// Output fp32 [B,T,C]. Compute in bf16 MFMA with fp32 accum.

typedef unsigned int u32;
typedef float  f32x4  __attribute__((ext_vector_type(4)));
typedef float  f32x16 __attribute__((ext_vector_type(16)));
typedef short  s16x8  __attribute__((ext_vector_type(8)));
typedef short  s16x4  __attribute__((ext_vector_type(4)));

#define MFMA_BF16(a, b, c) __builtin_amdgcn_mfma_f32_16x16x32_bf16((a), (b), (c), 0, 0, 0)
#define MFMA32(a, b, c)    __builtin_amdgcn_mfma_f32_32x32x16_bf16((a), (b), (c), 0, 0, 0)
#define LO4(v) __builtin_shufflevector((v), (v), 0, 1, 2, 3)
#define HI4(v) __builtin_shufflevector((v), (v), 4, 5, 6, 7)

#define GLOAD16(g, l)                                                        \
  __builtin_amdgcn_global_load_lds(                                          \
      (__attribute__((address_space(1))) void*)(g),                          \
      (__attribute__((address_space(3))) void*)(l), 16, 0, 0)

__device__ __forceinline__ unsigned short f2bf(float f) {
  union { float f; u32 u; } x; x.f = f;
  u32 r = (x.u + 0x7fffu + ((x.u >> 16) & 1u)) >> 16;
  return (unsigned short)r;
}

static __device__ __forceinline__ u32 cvtpk1(float a, float b) {
  u32 r;
  asm("v_cvt_pk_bf16_f32 %0, %1, %2" : "=v"(r) : "v"(a), "v"(b));
  return r;
}
static __device__ __forceinline__ void pl32swap(u32& a, u32& b) {
  asm("v_permlane32_swap_b32 %0, %1" : "+v"(a), "+v"(b));
}

// ---------------- kernel 1: x fp32 -> bf16 ----------------
__global__ void cvt_x_kernel(const float* __restrict__ x, unsigned short* __restrict__ xb) {
  int i = blockIdx.x * 256 + threadIdx.x;
  float4 v = ((const float4*)x)[i];
  ushort4 o;
  o.x = f2bf(v.x); o.y = f2bf(v.y); o.z = f2bf(v.z); o.w = f2bf(v.w);
  ((ushort4*)xb)[i] = o;
}

// ---------------- kernel 2: w [1024][3072] fp32 -> wT [3072][1024] bf16 ----
__global__ void transpose_w_kernel(const float* __restrict__ w, unsigned short* __restrict__ wT) {
  __shared__ unsigned short TL[64][72];
  const int tid = threadIdx.x;
  const int c0 = blockIdx.x * 64;
  const int r0 = blockIdx.y * 64;
#pragma unroll
  for (int p = 0; p < 4; ++p) {
    int r = p * 16 + (tid >> 4);
    int c = (tid & 15) * 4;
    float4 v = *(const float4*)&w[(size_t)(r0 + r) * 3072 + c0 + c];
    TL[c + 0][r] = f2bf(v.x);
    TL[c + 1][r] = f2bf(v.y);
    TL[c + 2][r] = f2bf(v.z);
    TL[c + 3][r] = f2bf(v.w);
  }
  __syncthreads();
#pragma unroll
  for (int p = 0; p < 4; ++p) {
    int c = p * 16 + (tid >> 4);
    int r = (tid & 15) * 4;
    ushort4 o;
    o.x = TL[c][r + 0]; o.y = TL[c][r + 1]; o.z = TL[c][r + 2]; o.w = TL[c][r + 3];
    *(ushort4*)&wT[(size_t)(c0 + c) * 1024 + r0 + r] = o;
  }
}

// ---------------- kernel 3: GEMM qkv = xb @ wT^T + bias ------------------
// bn<8: q (1/8-scaled) -> Qrm [4096][1024]; bn in [8,16): k -> Krm [4096][1024];
// bn>=16: v -> Vf frag-order: frag(bh,c,sb,dh) 1KB contiguous, elem
// (hiL*32+li)*8+e = V[s=c*32+sb*16+hiL*8+e][d=dh*32+li].
__global__ __launch_bounds__(256, 3) void gemm_qkv_kernel(
    const unsigned short* __restrict__ A, const unsigned short* __restrict__ Bt,
    const float* __restrict__ bias, unsigned short* __restrict__ Qrm,
    unsigned short* __restrict__ Krm, unsigned short* __restrict__ Vf) {
  __shared__ __align__(16) unsigned short SM[8448];   // As | Bs, reused as TL
  unsigned short* As = SM;
  unsigned short* Bs = SM + 4096;
  const int tid = threadIdx.x;
  const int lane = tid & 63, wid = tid >> 6;
  const int wr = wid >> 1, wc = wid & 1;
  const int g = lane >> 4, lm = lane & 15;
  const int bid = blockIdx.x;
  const int xcd = bid & 7, wl = bid >> 3;              // wl 0..95
  const int bn = wl % 24;
  const int bm = xcd * 4 + wl / 24;

  const unsigned short* gA = A  + (size_t)(bm * 128 + wid * 32 + (lane >> 2)) * 1024 + (lane & 3) * 8;
  const unsigned short* gB = Bt + (size_t)(bn * 128 + wid * 32 + (lane >> 2)) * 1024 + (lane & 3) * 8;
  unsigned short* lA0 = &As[wid * 1024];
  unsigned short* lA1 = &As[wid * 1024 + 512];
  unsigned short* lB0 = &Bs[wid * 1024];
  unsigned short* lB1 = &Bs[wid * 1024 + 512];

  f32x4 acc[4][4] = {};

  for (int kt = 0; kt < 32; ++kt) {
    __syncthreads();
    const unsigned short* a0 = gA + kt * 32;
    const unsigned short* b0 = gB + kt * 32;
    GLOAD16(a0,             lA0);
    GLOAD16(a0 + 16 * 1024, lA1);
    GLOAD16(b0,             lB0);
    GLOAD16(b0 + 16 * 1024, lB1);
    __syncthreads();

    s16x8 af[4], bf[4];
#pragma unroll
    for (int m = 0; m < 4; ++m)
      af[m] = *(const s16x8*)&As[(wr * 64 + m * 16 + lm) * 32 + g * 8];
#pragma unroll
    for (int n = 0; n < 4; ++n)
      bf[n] = *(const s16x8*)&Bs[(wc * 64 + n * 16 + lm) * 32 + g * 8];
#pragma unroll
    for (int m = 0; m < 4; ++m)
#pragma unroll
      for (int n = 0; n < 4; ++n)
        acc[m][n] = MFMA_BF16(af[m], bf[n], acc[m][n]);
  }

  if (bn < 8) {                                  // q, pre-scaled by 1/8
#pragma unroll
    for (int m = 0; m < 4; ++m) {
      const int row = bm * 128 + wr * 64 + m * 16 + g * 4;
#pragma unroll
      for (int n = 0; n < 4; ++n) {
        const int col = bn * 128 + wc * 64 + n * 16 + lm;
        const float bv = bias[col];
#pragma unroll
        for (int r = 0; r < 4; ++r)
          Qrm[(size_t)(row + r) * 1024 + col] = f2bf((acc[m][n][r] + bv) * 0.125f);
      }
    }
  } else if (bn < 16) {                          // k, row-major
#pragma unroll
    for (int m = 0; m < 4; ++m) {
      const int row = bm * 128 + wr * 64 + m * 16 + g * 4;
#pragma unroll
      for (int n = 0; n < 4; ++n) {
        const int col = bn * 128 + wc * 64 + n * 16 + lm;     // 1024..2047
        const float bv = bias[col];
#pragma unroll
        for (int r = 0; r < 4; ++r)
          Krm[(size_t)(row + r) * 1024 + (col - 1024)] = f2bf(acc[m][n][r] + bv);
      }
    }
  } else {                                       // v -> Vf frag-order via LDS
    unsigned short* TL = SM;                     // [64 d][132 t-pad]
    const int bb = bm >> 4, bmt = bm & 15;       // b, t-block
    __syncthreads();                             // As/Bs reads done
#pragma unroll
    for (int p = 0; p < 2; ++p) {
      const int h = (bn - 16) * 2 + p;           // this pass's head
      const size_t fb = (size_t)(bb * 16 + h) * 64 * 4;   // frag base
      if (wc == p) {
#pragma unroll
        for (int m = 0; m < 4; ++m) {
          const int r = wr * 64 + m * 16 + g * 4;
#pragma unroll
          for (int n = 0; n < 4; ++n) {
            const int c = n * 16 + lm;           // d 0..63
            const float bv = bias[2048 + h * 64 + c];
            ushort4 o;
#pragma unroll
            for (int r2 = 0; r2 < 4; ++r2)
              ((unsigned short*)&o)[r2] = f2bf(acc[m][n][r2] + bv);
            *(ushort4*)&TL[c * 132 + r] = o;
          }
        }
      }
      __syncthreads();
      const int li = tid & 31, grp = tid >> 5;
      const int dh = grp & 1, oct8 = grp >> 1;
      const int cl = dh * 32 + li;               // d
#pragma unroll
      for (int k2 = 0; k2 < 4; ++k2) {
        const int oct = oct8 * 4 + k2;           // t-octet 0..15
        const int c = bmt * 4 + (oct >> 2);
        const int sb = (oct >> 1) & 1, hiL2 = oct & 1;
        union { s16x8 v; s16x4 hv[2]; } o;
        o.hv[0] = *(const s16x4*)&TL[cl * 132 + oct * 8];
        o.hv[1] = *(const s16x4*)&TL[cl * 132 + oct * 8 + 4];
        *(s16x8*)&Vf[(fb + (size_t)c * 4 + sb * 2 + dh) * 512 + (hiL2 * 32 + li) * 8] = o.v;
      }
      __syncthreads();
    }
  }
}

// ---------------- kernel 4: K row-major -> Kf frag-order ------------------
// frag(bh,c,m) 1KB contiguous, elem (hiL*32+li)*8+e = K[s=c*32+li][d=m*16+hiL*8+e]
__global__ __launch_bounds__(256) void krelayout_kernel(
    const unsigned short* __restrict__ Krm, unsigned short* __restrict__ Kf) {
  __shared__ unsigned short TL[64 * 68];         // [s 0..63][d 0..63 +4]
  const int tid = threadIdx.x;
  const int cg = blockIdx.x;                     // 0..31 (64 s rows)
  const int bh = blockIdx.y;                     // 0..31
  const int b = bh >> 4, h = bh & 15;
  const int s_loc = tid >> 2, pq = tid & 3;
  const unsigned short* src = &Krm[(size_t)(b * 2048 + cg * 64 + s_loc) * 1024 + h * 64];
  s16x8 u0 = *(const s16x8*)&src[pq * 8];
  s16x8 u1 = *(const s16x8*)&src[(pq + 4) * 8];
  unsigned short* t0 = &TL[s_loc * 68 + pq * 8];
  *(s16x4*)(t0)            = LO4(u0);
  *(s16x4*)(t0 + 4)        = HI4(u0);
  *(s16x4*)(t0 + 32)       = LO4(u1);
  *(s16x4*)(t0 + 36)       = HI4(u1);
  __syncthreads();
  const int l = tid & 63, fi = tid >> 6;
  const int hiL = l >> 5, li = l & 31;
#pragma unroll
  for (int ff = 0; ff < 2; ++ff) {
    const int fr = ff * 4 + fi;                  // 0..7
    const int c_loc = fr >> 2, m = fr & 3;
    const unsigned short* tp = &TL[(c_loc * 32 + li) * 68 + m * 16 + hiL * 8];
    union { s16x8 v; s16x4 hv[2]; } o;
    o.hv[0] = *(const s16x4*)(tp);
    o.hv[1] = *(const s16x4*)(tp + 4);
    *(s16x8*)&Kf[(((size_t)bh * 64 + cg * 2 + c_loc) * 4 + m) * 512 + l * 8] = o.v;
  }
}

// ---------------- kernel 5: attention v9 ----------------------------------
// 512 blocks (2/CU, independent barrier domains) x 4 warps. Block owns 64-row
// q-tiles (31-j, j) sequentially: 33 uniform steps of 64 s. Warp (wt, half):
// 32 q-rows (wt) x s-half (half). Staging = global_load_lds straight from
// frag-order Kf/Vf (one wave-uniform 1KB load per fragment) into frag-order
// LDS, double-buffered, issued one step ahead. Compute: swapped mfma32 QK^T,
// cvt_pk+permlane32 P, mfma32 PV. s-half partials merged via LDS at tile end.
__global__ __launch_bounds__(256, 2) void attn_kernel(
    const unsigned short* __restrict__ Qrm, const unsigned short* __restrict__ Kf,
    const unsigned short* __restrict__ Vf, float* __restrict__ out) {
  __shared__ __align__(16) unsigned short Ks[2][4096];
  __shared__ __align__(16) unsigned short Vs[2][4096];
  const int tid = threadIdx.x, lane = tid & 63, w = tid >> 6;   // w 0..3
  const int hiL = lane >> 5, li = lane & 31;
  const int wt = w >> 1, half = w & 1;
  const int bid = blockIdx.x;
  const int xcd = bid & 7, rest = bid >> 3;      // rest 0..63
  const int bh = xcd * 4 + (rest >> 4);          // XCD-pinned (b,h)
  const int j = rest & 15;
  const int b = bh >> 4, h = bh & 15;
  const int thi = 31 - j, tlo = j;               // 64-row tiles
  const unsigned short* Kb = Kf + (size_t)bh * 64 * 2048;
  const unsigned short* Vb = Vf + (size_t)bh * 64 * 2048;
  const size_t qstr = (size_t)(b * 2048) * 1024 + h * 64 + hiL * 8;

#define STAGE(buf, stx)                                                      \
  do {                                                                       \
    const unsigned short* kk = Kb + (size_t)(stx) * 8 * 512 + lane * 8;      \
    const unsigned short* vv = Vb + (size_t)(stx) * 8 * 512 + lane * 8;      \
    if (w < 2) {                                                             \
      _Pragma("unroll")                                                      \
      for (int f = 0; f < 4; ++f)                                            \
        GLOAD16(kk + (w * 4 + f) * 512, &Ks[buf][(w * 4 + f) * 512]);        \
    } else {                                                                 \
      _Pragma("unroll")                                                      \
      for (int f = 0; f < 4; ++f)                                            \
        GLOAD16(vv + ((w - 2) * 4 + f) * 512, &Vs[buf][((w - 2) * 4 + f) * 512]); \
    }                                                                        \
  } while (0)

  int qrow0 = thi * 64 + wt * 32;
  s16x8 qf0, qf1, qf2, qf3;
  {
    const unsigned short* qp = &Qrm[qstr + (size_t)(qrow0 + li) * 1024];
    qf0 = *(const s16x8*)(qp);      qf1 = *(const s16x8*)(qp + 16);
    qf2 = *(const s16x8*)(qp + 32); qf3 = *(const s16x8*)(qp + 48);
  }
  f32x16 y0 = {}, y1 = {};

  STAGE(0, 0);                                   // tile thi, step 0
  __syncthreads();

  int cur = 0;
  for (int u = 0; u < 33; ++u) {
    const int tl = (u <= thi) ? thi : tlo;
    const int st = (u <= thi) ? u : (u - thi - 1);
    if (u < 32) {                                // issue next step's stage
      const int un = u + 1;
      const int stn = (un <= thi) ? un : (un - thi - 1);
      STAGE(cur ^ 1, stn);
    }
    const int sEff = st * 64 + half * 32;
    if ((st < tl) || (half <= wt)) {             // causally active
      const unsigned short* Kc = &Ks[cur][half * 2048];
      const unsigned short* Vc = &Vs[cur][half * 2048];
      const bool dm = (st == tl) && (half == wt);
      __builtin_amdgcn_s_setprio(1);
      f32x16 sacc = {};
      sacc = MFMA32(*(const s16x8*)(Kc + 0 * 512 + lane * 8), qf0, sacc);
      sacc = MFMA32(*(const s16x8*)(Kc + 1 * 512 + lane * 8), qf1, sacc);
      sacc = MFMA32(*(const s16x8*)(Kc + 2 * 512 + lane * 8), qf2, sacc);
      sacc = MFMA32(*(const s16x8*)(Kc + 3 * 512 + lane * 8), qf3, sacc);
      float pr[16];
#pragma unroll
      for (int r = 0; r < 16; ++r) {
        float v = sacc[r] > 0.f ? sacc[r] : 0.f;
        if (dm) {
          const int sg = sEff + (r & 3) + 8 * (r >> 2) + 4 * hiL;
          if (sg > qrow0 + li) v = 0.f;
        }
        pr[r] = v;
      }
#pragma unroll
      for (int hh = 0; hh < 2; ++hh) {
        u32 a0 = cvtpk1(pr[8 * hh + 0], pr[8 * hh + 1]);
        u32 b0 = cvtpk1(pr[8 * hh + 4], pr[8 * hh + 5]);
        u32 a1 = cvtpk1(pr[8 * hh + 2], pr[8 * hh + 3]);
        u32 b1 = cvtpk1(pr[8 * hh + 6], pr[8 * hh + 7]);
        pl32swap(a0, b0);
        pl32swap(a1, b1);
        union { s16x8 v; u32 wv[4]; } pa;
        pa.wv[0] = a0; pa.wv[1] = a1; pa.wv[2] = b0; pa.wv[3] = b1;
        const s16x8 vA = *(const s16x8*)(Vc + (hh * 2 + 0) * 512 + lane * 8);
        const s16x8 vB = *(const s16x8*)(Vc + (hh * 2 + 1) * 512 + lane * 8);
        y0 = MFMA32(pa.v, vA, y0);
        y1 = MFMA32(pa.v, vB, y1);
      }
      __builtin_amdgcn_s_setprio(0);
    }
    if (st == tl) {                              // tile end: merge halves, store
      __syncthreads();                           // all frag reads of cur done
      float* M = wt ? (float*)&Vs[cur][0] : (float*)&Ks[cur][0];
      if (half == 0) {
#pragma unroll
        for (int r = 0; r < 16; ++r) {
          const int ql = (r & 3) + 8 * (r >> 2) + 4 * hiL;
          M[ql * 64 + li]      = y0[r];
          M[ql * 64 + li + 32] = y1[r];
        }
      }
      __syncthreads();
      if (half == 1) {
        const size_t ob = (size_t)(b * 2048 + qrow0) * 1024 + h * 64 + li;
#pragma unroll
        for (int r = 0; r < 16; ++r) {
          const int ql = (r & 3) + 8 * (r >> 2) + 4 * hiL;
          out[ob + (size_t)ql * 1024]      = y0[r] + M[ql * 64 + li];
          out[ob + (size_t)ql * 1024 + 32] = y1[r] + M[ql * 64 + li + 32];
        }
      }
      if (u < 32) {                              // switch to tile tlo
        qrow0 = tlo * 64 + wt * 32;
        const unsigned short* qp = &Qrm[qstr + (size_t)(qrow0 + li) * 1024];
        qf0 = *(const s16x8*)(qp);      qf1 = *(const s16x8*)(qp + 16);
        qf2 = *(const s16x8*)(qp + 32); qf3 = *(const s16x8*)(qp + 48);
        y0 = (f32x16){}; y1 = (f32x16){};
      }
    }
    __syncthreads();                             // step end (drains gloads)
    cur ^= 1;
  }
#undef STAGE
}

extern "C" void kernel_launch(void* const* d_in, const int* in_sizes, int n_in,
                              void* d_out, int out_size, void* d_ws, size_t ws_size,
                              hipStream_t stream) {
  const float* x    = (const float*)d_in[0];
  const float* w    = (const float*)d_in[1];
  const float* bias = (const float*)d_in[2];
  float* out = (float*)d_out;

  unsigned short* xb  = (unsigned short*)d_ws;            // 4096*1024
  unsigned short* wT  = xb  + (size_t)4096 * 1024;        // 3072*1024
  unsigned short* Qrm = wT  + (size_t)3072 * 1024;        // 4096*1024
  unsigned short* Krm = Qrm + (size_t)4096 * 1024;        // 4096*1024
  unsigned short* Kf  = Krm + (size_t)4096 * 1024;        // 4096*1024
  unsigned short* Vf  = Kf  + (size_t)4096 * 1024;        // 4096*1024

  cvt_x_kernel<<<4096, 256, 0, stream>>>(x, xb);
  transpose_w_kernel<<<dim3(48, 16), 256, 0, stream>>>(w, wT);
  gemm_qkv_kernel<<<768, 256, 0, stream>>>(xb, wT, bias, Qrm, Krm, Vf);
  krelayout_kernel<<<dim3(32, 32), 256, 0, stream>>>(Krm, Kf);
  attn_kernel<<<512, 256, 0, stream>>>(Qrm, Kf, Vf, out);
}

// Round 10
// 79.211 us; speedup vs baseline: 1.1221x; 1.0543x over previous
//
#include <hip/hip_runtime.h>

// Problem: B=2, T=2048, C=1024, H=16, D=64
// qkv = x @ w + b ; q,k,v split; att = relu(causal(q k^T / 8)); y = att @ v
// Output fp32 [B,T,C]. Compute in bf16 MFMA with fp32 accum.

typedef unsigned int u32;
typedef float  f32x4  __attribute__((ext_vector_type(4)));
typedef float  f32x16 __attribute__((ext_vector_type(16)));
typedef short  s16x8  __attribute__((ext_vector_type(8)));
typedef short  s16x4  __attribute__((ext_vector_type(4)));

#define MFMA_BF16(a, b, c) __builtin_amdgcn_mfma_f32_16x16x32_bf16((a), (b), (c), 0, 0, 0)
#define MFMA32(a, b, c)    __builtin_amdgcn_mfma_f32_32x32x16_bf16((a), (b), (c), 0, 0, 0)
#define LO4(v) __builtin_shufflevector((v), (v), 0, 1, 2, 3)
#define HI4(v) __builtin_shufflevector((v), (v), 4, 5, 6, 7)

#define GLOAD16(g, l)                                                        \
  __builtin_amdgcn_global_load_lds(                                          \
      (__attribute__((address_space(1))) void*)(g),                          \
      (__attribute__((address_space(3))) void*)(l), 16, 0, 0)

__device__ __forceinline__ unsigned short f2bf(float f) {
  union { float f; u32 u; } x; x.f = f;
  u32 r = (x.u + 0x7fffu + ((x.u >> 16) & 1u)) >> 16;
  return (unsigned short)r;
}

static __device__ __forceinline__ u32 cvtpk1(float a, float b) {
  u32 r;
  asm("v_cvt_pk_bf16_f32 %0, %1, %2" : "=v"(r) : "v"(a), "v"(b));
  return r;
}
static __device__ __forceinline__ void pl32swap(u32& a, u32& b) {
  asm("v_permlane32_swap_b32 %0, %1" : "+v"(a), "+v"(b));
}

// ---------------- kernel 1: x fp32 -> bf16 ----------------
__global__ void cvt_x_kernel(const float* __restrict__ x, unsigned short* __restrict__ xb) {
  int i = blockIdx.x * 256 + threadIdx.x;
  float4 v = ((const float4*)x)[i];
  ushort4 o;
  o.x = f2bf(v.x); o.y = f2bf(v.y); o.z = f2bf(v.z); o.w = f2bf(v.w);
  ((ushort4*)xb)[i] = o;
}

// ---------------- kernel 2: w [1024][3072] fp32 -> wT [3072][1024] bf16 ----
__global__ void transpose_w_kernel(const float* __restrict__ w, unsigned short* __restrict__ wT) {
  __shared__ unsigned short TL[64][72];
  const int tid = threadIdx.x;
  const int c0 = blockIdx.x * 64;
  const int r0 = blockIdx.y * 64;
#pragma unroll
  for (int p = 0; p < 4; ++p) {
    int r = p * 16 + (tid >> 4);
    int c = (tid & 15) * 4;
    float4 v = *(const float4*)&w[(size_t)(r0 + r) * 3072 + c0 + c];
    TL[c + 0][r] = f2bf(v.x);
    TL[c + 1][r] = f2bf(v.y);
    TL[c + 2][r] = f2bf(v.z);
    TL[c + 3][r] = f2bf(v.w);
  }
  __syncthreads();
#pragma unroll
  for (int p = 0; p < 4; ++p) {
    int c = p * 16 + (tid >> 4);
    int r = (tid & 15) * 4;
    ushort4 o;
    o.x = TL[c][r + 0]; o.y = TL[c][r + 1]; o.z = TL[c][r + 2]; o.w = TL[c][r + 3];
    *(ushort4*)&wT[(size_t)(c0 + c) * 1024 + r0 + r] = o;
  }
}

// ---------------- kernel 3: GEMM qkv = xb @ wT^T + bias ------------------
// bn<8:  q (1/8-scaled) -> Qrm [4096][1024] row-major
// bn<16: k -> Kf frag-order directly (TL untransposed, 2 t-half passes)
// else:  v -> Vf frag-order (TL transposed, 2 head passes)
// Kf frag(bh,c,m): elem l*8+e = K[s=c*32+(l&31)][d=m*16+(l>>5)*8+e]
// Vf frag(bh,c,sb,dh): elem l*8+e = V[s=c*32+sb*16+(l>>5)*8+e][d=dh*32+(l&31)]
__global__ __launch_bounds__(256, 3) void gemm_qkv_kernel(
    const unsigned short* __restrict__ A, const unsigned short* __restrict__ Bt,
    const float* __restrict__ bias, unsigned short* __restrict__ Qrm,
    unsigned short* __restrict__ Kf, unsigned short* __restrict__ Vf) {
  __shared__ __align__(16) unsigned short SM[8448];   // As | Bs, reused as TL
  unsigned short* As = SM;
  unsigned short* Bs = SM + 4096;
  const int tid = threadIdx.x;
  const int lane = tid & 63, wid = tid >> 6;
  const int wr = wid >> 1, wc = wid & 1;
  const int g = lane >> 4, lm = lane & 15;
  const int bid = blockIdx.x;
  const int xcd = bid & 7, wl = bid >> 3;              // wl 0..95
  const int bn = wl % 24;
  const int bm = xcd * 4 + wl / 24;

  const unsigned short* gA = A  + (size_t)(bm * 128 + wid * 32 + (lane >> 2)) * 1024 + (lane & 3) * 8;
  const unsigned short* gB = Bt + (size_t)(bn * 128 + wid * 32 + (lane >> 2)) * 1024 + (lane & 3) * 8;
  unsigned short* lA0 = &As[wid * 1024];
  unsigned short* lA1 = &As[wid * 1024 + 512];
  unsigned short* lB0 = &Bs[wid * 1024];
  unsigned short* lB1 = &Bs[wid * 1024 + 512];

  f32x4 acc[4][4] = {};

  for (int kt = 0; kt < 32; ++kt) {
    __syncthreads();
    const unsigned short* a0 = gA + kt * 32;
    const unsigned short* b0 = gB + kt * 32;
    GLOAD16(a0,             lA0);
    GLOAD16(a0 + 16 * 1024, lA1);
    GLOAD16(b0,             lB0);
    GLOAD16(b0 + 16 * 1024, lB1);
    __syncthreads();

    s16x8 af[4], bf[4];
#pragma unroll
    for (int m = 0; m < 4; ++m)
      af[m] = *(const s16x8*)&As[(wr * 64 + m * 16 + lm) * 32 + g * 8];
#pragma unroll
    for (int n = 0; n < 4; ++n)
      bf[n] = *(const s16x8*)&Bs[(wc * 64 + n * 16 + lm) * 32 + g * 8];
#pragma unroll
    for (int m = 0; m < 4; ++m)
#pragma unroll
      for (int n = 0; n < 4; ++n)
        acc[m][n] = MFMA_BF16(af[m], bf[n], acc[m][n]);
  }

  const int bb = bm >> 4;                        // batch
  if (bn < 8) {                                  // q, pre-scaled by 1/8
#pragma unroll
    for (int m = 0; m < 4; ++m) {
      const int row = bm * 128 + wr * 64 + m * 16 + g * 4;
#pragma unroll
      for (int n = 0; n < 4; ++n) {
        const int col = bn * 128 + wc * 64 + n * 16 + lm;
        const float bv = bias[col];
#pragma unroll
        for (int r = 0; r < 4; ++r)
          Qrm[(size_t)(row + r) * 1024 + col] = f2bf((acc[m][n][r] + bv) * 0.125f);
      }
    }
  } else if (bn < 16) {                          // k -> Kf frag-order via TL
    unsigned short* TL = SM;                     // [64 t][132] (128 cols + pad)
    __syncthreads();                             // As/Bs reads done
#pragma unroll
    for (int p = 0; p < 2; ++p) {                // t-half
      if (wr == p) {
#pragma unroll
        for (int m = 0; m < 4; ++m) {
#pragma unroll
          for (int n = 0; n < 4; ++n) {
            const int col = wc * 64 + n * 16 + lm;          // 0..127 (2 heads)
            const float bv = bias[1024 + (bn - 8) * 128 + col];
#pragma unroll
            for (int r = 0; r < 4; ++r)
              TL[(m * 16 + g * 4 + r) * 132 + col] = f2bf(acc[m][n][r] + bv);
          }
        }
      }
      __syncthreads();
      const int li2 = lane & 31, hiL2 = lane >> 5;
#pragma unroll
      for (int f = 0; f < 4; ++f) {
        const int frag = f * 4 + wid;            // 0..15
        const int c_loc = frag >> 3, head = (frag >> 2) & 1, m = frag & 3;
        const int hg = (bn - 8) * 2 + head;
        const int c = (bm & 15) * 4 + p * 2 + c_loc;
        s16x8 o = *(const s16x8*)&TL[(c_loc * 32 + li2) * 132 + head * 64 + m * 16 + hiL2 * 8];
        *(s16x8*)&Kf[(((size_t)(bb * 16 + hg) * 64 + c) * 4 + m) * 512 + lane * 8] = o;
      }
      __syncthreads();
    }
  } else {                                       // v -> Vf frag-order via TL
    unsigned short* TL = SM;                     // [64 d][132 t-pad]
    const int bmt = bm & 15;                     // t-block
    __syncthreads();                             // As/Bs reads done
#pragma unroll
    for (int p = 0; p < 2; ++p) {
      const int h = (bn - 16) * 2 + p;           // this pass's head
      const size_t fb = (size_t)(bb * 16 + h) * 64 * 4;   // frag base
      if (wc == p) {
#pragma unroll
        for (int m = 0; m < 4; ++m) {
          const int r = wr * 64 + m * 16 + g * 4;
#pragma unroll
          for (int n = 0; n < 4; ++n) {
            const int c = n * 16 + lm;           // d 0..63
            const float bv = bias[2048 + h * 64 + c];
            ushort4 o;
#pragma unroll
            for (int r2 = 0; r2 < 4; ++r2)
              ((unsigned short*)&o)[r2] = f2bf(acc[m][n][r2] + bv);
            *(ushort4*)&TL[c * 132 + r] = o;
          }
        }
      }
      __syncthreads();
      const int li = tid & 31, grp = tid >> 5;
      const int dh = grp & 1, oct8 = grp >> 1;
      const int cl = dh * 32 + li;               // d
#pragma unroll
      for (int k2 = 0; k2 < 4; ++k2) {
        const int oct = oct8 * 4 + k2;           // t-octet 0..15
        const int c = bmt * 4 + (oct >> 2);
        const int sb = (oct >> 1) & 1, hiL2 = oct & 1;
        union { s16x8 v; s16x4 hv[2]; } o;
        o.hv[0] = *(const s16x4*)&TL[cl * 132 + oct * 8];
        o.hv[1] = *(const s16x4*)&TL[cl * 132 + oct * 8 + 4];
        *(s16x8*)&Vf[(fb + (size_t)c * 4 + sb * 2 + dh) * 512 + (hiL2 * 32 + li) * 8] = o.v;
      }
      __syncthreads();
    }
  }
}

// ---------------- kernel 4: attention v10 (v9 + T15 deferred PV) ----------
// 512 blocks (2/CU) x 4 warps; block owns 64-row tiles (31-j, j): 33 steps.
// Warp (wt, half): 32 q-rows x s-half. Staging = global_load_lds from
// frag-order Kf/Vf (wave-uniform 1KB loads), double-buffered, 1 step ahead.
// T15: V frags of step u ds_read to regs at step u; PV(u) executes at the
// top of step u+1 back-to-back with QK(u+1) (independent MFMA burst), the
// relu/cvt VALU of u+1 overlaps. QK split into 2 indep accumulation chains.
__global__ __launch_bounds__(256, 2) void attn_kernel(
    const unsigned short* __restrict__ Qrm, const unsigned short* __restrict__ Kf,
    const unsigned short* __restrict__ Vf, float* __restrict__ out) {
  __shared__ __align__(16) unsigned short Ks[2][4096];
  __shared__ __align__(16) unsigned short Vs[2][4096];
  const int tid = threadIdx.x, lane = tid & 63, w = tid >> 6;   // w 0..3
  const int hiL = lane >> 5, li = lane & 31;
  const int wt = w >> 1, half = w & 1;
  const int bid = blockIdx.x;
  const int xcd = bid & 7, rest = bid >> 3;      // rest 0..63
  const int bh = xcd * 4 + (rest >> 4);          // XCD-pinned (b,h)
  const int j = rest & 15;
  const int b = bh >> 4, h = bh & 15;
  const int thi = 31 - j, tlo = j;               // 64-row tiles
  const unsigned short* Kb = Kf + (size_t)bh * 64 * 2048;
  const unsigned short* Vb = Vf + (size_t)bh * 64 * 2048;
  const size_t qstr = (size_t)(b * 2048) * 1024 + h * 64 + hiL * 8;

#define STAGE(buf, stx)                                                      \
  do {                                                                       \
    const unsigned short* kk = Kb + (size_t)(stx) * 8 * 512 + lane * 8;      \
    const unsigned short* vv = Vb + (size_t)(stx) * 8 * 512 + lane * 8;      \
    if (w < 2) {                                                             \
      _Pragma("unroll")                                                      \
      for (int f = 0; f < 4; ++f)                                            \
        GLOAD16(kk + (w * 4 + f) * 512, &Ks[buf][(w * 4 + f) * 512]);        \
    } else {                                                                 \
      _Pragma("unroll")                                                      \
      for (int f = 0; f < 4; ++f)                                            \
        GLOAD16(vv + ((w - 2) * 4 + f) * 512, &Vs[buf][((w - 2) * 4 + f) * 512]); \
    }                                                                        \
  } while (0)

// SM: pr[] -> pa0s, pa1s
#define PACK_PA()                                                            \
  do {                                                                       \
    u32 a0 = cvtpk1(pr[0], pr[1]);                                           \
    u32 b0 = cvtpk1(pr[4], pr[5]);                                           \
    u32 a1 = cvtpk1(pr[2], pr[3]);                                           \
    u32 b1 = cvtpk1(pr[6], pr[7]);                                           \
    pl32swap(a0, b0); pl32swap(a1, b1);                                      \
    union { s16x8 v; u32 wv[4]; } pk0;                                       \
    pk0.wv[0] = a0; pk0.wv[1] = a1; pk0.wv[2] = b0; pk0.wv[3] = b1;          \
    pa0s = pk0.v;                                                            \
    u32 c0 = cvtpk1(pr[8], pr[9]);                                           \
    u32 d0 = cvtpk1(pr[12], pr[13]);                                         \
    u32 c1 = cvtpk1(pr[10], pr[11]);                                         \
    u32 d1 = cvtpk1(pr[14], pr[15]);                                         \
    pl32swap(c0, d0); pl32swap(c1, d1);                                      \
    union { s16x8 v; u32 wv[4]; } pk1;                                       \
    pk1.wv[0] = c0; pk1.wv[1] = c1; pk1.wv[2] = d0; pk1.wv[3] = d1;          \
    pa1s = pk1.v;                                                            \
  } while (0)

  int qrow0 = thi * 64 + wt * 32;
  s16x8 qf0, qf1, qf2, qf3;
  {
    const unsigned short* qp = &Qrm[qstr + (size_t)(qrow0 + li) * 1024];
    qf0 = *(const s16x8*)(qp);      qf1 = *(const s16x8*)(qp + 16);
    qf2 = *(const s16x8*)(qp + 32); qf3 = *(const s16x8*)(qp + 48);
  }
  f32x16 y0 = {}, y1 = {};
  s16x8 pa0s = {}, pa1s = {}, vv0 = {}, vv1 = {}, vv2 = {}, vv3 = {};
  bool have_prev = false;

  STAGE(0, 0);
  __syncthreads();

  int cur = 0;
  for (int u = 0; u < 33; ++u) {
    const int tl = (u <= thi) ? thi : tlo;
    const int st = (u <= thi) ? u : (u - thi - 1);
    if (u < 32) {                                // issue next step's stage
      const int un = u + 1;
      const int stn = (un <= thi) ? un : (un - thi - 1);
      STAGE(cur ^ 1, stn);
    }
    const unsigned short* Kc = &Ks[cur][half * 2048];
    const unsigned short* Vc = &Vs[cur][half * 2048];

    __builtin_amdgcn_s_setprio(1);
    if (have_prev) {                             // PV(u-1): indep MFMA burst
      y0 = MFMA32(pa0s, vv0, y0);
      y1 = MFMA32(pa0s, vv1, y1);
      y0 = MFMA32(pa1s, vv2, y0);
      y1 = MFMA32(pa1s, vv3, y1);
    }
    if (st < tl) {                               // full step: defer PV
      f32x16 sa = {}, sb = {};
      sa = MFMA32(*(const s16x8*)(Kc + 0 * 512 + lane * 8), qf0, sa);
      sa = MFMA32(*(const s16x8*)(Kc + 1 * 512 + lane * 8), qf1, sa);
      sb = MFMA32(*(const s16x8*)(Kc + 2 * 512 + lane * 8), qf2, sb);
      sb = MFMA32(*(const s16x8*)(Kc + 3 * 512 + lane * 8), qf3, sb);
      vv0 = *(const s16x8*)(Vc + 0 * 512 + lane * 8);
      vv1 = *(const s16x8*)(Vc + 1 * 512 + lane * 8);
      vv2 = *(const s16x8*)(Vc + 2 * 512 + lane * 8);
      vv3 = *(const s16x8*)(Vc + 3 * 512 + lane * 8);
      __builtin_amdgcn_s_setprio(0);
      float pr[16];
#pragma unroll
      for (int r = 0; r < 16; ++r) {
        const float v = sa[r] + sb[r];
        pr[r] = v > 0.f ? v : 0.f;
      }
      PACK_PA();
      have_prev = true;
    } else {                                     // tile-end step
      if (half <= wt) {                          // causally active
        f32x16 sa = {}, sb = {};
        sa = MFMA32(*(const s16x8*)(Kc + 0 * 512 + lane * 8), qf0, sa);
        sa = MFMA32(*(const s16x8*)(Kc + 1 * 512 + lane * 8), qf1, sa);
        sb = MFMA32(*(const s16x8*)(Kc + 2 * 512 + lane * 8), qf2, sb);
        sb = MFMA32(*(const s16x8*)(Kc + 3 * 512 + lane * 8), qf3, sb);
        vv0 = *(const s16x8*)(Vc + 0 * 512 + lane * 8);
        vv1 = *(const s16x8*)(Vc + 1 * 512 + lane * 8);
        vv2 = *(const s16x8*)(Vc + 2 * 512 + lane * 8);
        vv3 = *(const s16x8*)(Vc + 3 * 512 + lane * 8);
        const int sEff = st * 64 + half * 32;
        float pr[16];
#pragma unroll
        for (int r = 0; r < 16; ++r) {
          float v = sa[r] + sb[r];
          v = v > 0.f ? v : 0.f;
          if (half == wt) {                      // diagonal mask
            const int sg = sEff + (r & 3) + 8 * (r >> 2) + 4 * hiL;
            if (sg > qrow0 + li) v = 0.f;
          }
          pr[r] = v;
        }
        PACK_PA();
        y0 = MFMA32(pa0s, vv0, y0);              // PV immediate (pre-flush)
        y1 = MFMA32(pa0s, vv1, y1);
        y0 = MFMA32(pa1s, vv2, y0);
        y1 = MFMA32(pa1s, vv3, y1);
      }
      __builtin_amdgcn_s_setprio(0);
      have_prev = false;
      // merge s-halves via consumed LDS buffer, store
      __syncthreads();                           // all frag reads of cur done
      float* M = wt ? (float*)&Vs[cur][0] : (float*)&Ks[cur][0];
      if (half == 0) {
#pragma unroll
        for (int r = 0; r < 16; ++r) {
          const int ql = (r & 3) + 8 * (r >> 2) + 4 * hiL;
          M[ql * 64 + li]      = y0[r];
          M[ql * 64 + li + 32] = y1[r];
        }
      }
      __syncthreads();
      if (half == 1) {
        const size_t ob = (size_t)(b * 2048 + qrow0) * 1024 + h * 64 + li;
#pragma unroll
        for (int r = 0; r < 16; ++r) {
          const int ql = (r & 3) + 8 * (r >> 2) + 4 * hiL;
          out[ob + (size_t)ql * 1024]      = y0[r] + M[ql * 64 + li];
          out[ob + (size_t)ql * 1024 + 32] = y1[r] + M[ql * 64 + li + 32];
        }
      }
      if (u < 32) {                              // switch to tile tlo
        qrow0 = tlo * 64 + wt * 32;
        const unsigned short* qp = &Qrm[qstr + (size_t)(qrow0 + li) * 1024];
        qf0 = *(const s16x8*)(qp);      qf1 = *(const s16x8*)(qp + 16);
        qf2 = *(const s16x8*)(qp + 32); qf3 = *(const s16x8*)(qp + 48);
        y0 = (f32x16){}; y1 = (f32x16){};
      }
    }
    __syncthreads();                             // step end (drains gloads)
    cur ^= 1;
  }
#undef STAGE
#undef PACK_PA
}

extern "C" void kernel_launch(void* const* d_in, const int* in_sizes, int n_in,
                              void* d_out, int out_size, void* d_ws, size_t ws_size,
                              hipStream_t stream) {
  const float* x    = (const float*)d_in[0];
  const float* w    = (const float*)d_in[1];
  const float* bias = (const float*)d_in[2];
  float* out = (float*)d_out;

  unsigned short* xb  = (unsigned short*)d_ws;            // 4096*1024
  unsigned short* wT  = xb  + (size_t)4096 * 1024;        // 3072*1024
  unsigned short* Qrm = wT  + (size_t)3072 * 1024;        // 4096*1024
  unsigned short* Kf  = Qrm + (size_t)4096 * 1024;        // 4096*1024 (frag-order)
  unsigned short* Vf  = Kf  + (size_t)4096 * 1024;        // 4096*1024 (frag-order)

  cvt_x_kernel<<<4096, 256, 0, stream>>>(x, xb);
  transpose_w_kernel<<<dim3(48, 16), 256, 0, stream>>>(w, wT);
  gemm_qkv_kernel<<<768, 256, 0, stream>>>(xb, wT, bias, Qrm, Kf, Vf);
  attn_kernel<<<512, 256, 0, stream>>>(Qrm, Kf, Vf, out);
}

// Round 11
// 76.905 us; speedup vs baseline: 1.1558x; 1.0300x over previous
//
#include <hip/hip_runtime.h>

// Problem: B=2, T=2048, C=1024, H=16, D=64
// qkv = x @ w + b ; q,k,v split; att = relu(causal(q k^T / 8)); y = att @ v
// Output fp32 [B,T,C]. Compute in bf16 MFMA with fp32 accum.

typedef unsigned int u32;
typedef float  f32x4  __attribute__((ext_vector_type(4)));
typedef float  f32x16 __attribute__((ext_vector_type(16)));
typedef short  s16x8  __attribute__((ext_vector_type(8)));
typedef short  s16x4  __attribute__((ext_vector_type(4)));

#define MFMA_BF16(a, b, c) __builtin_amdgcn_mfma_f32_16x16x32_bf16((a), (b), (c), 0, 0, 0)
#define MFMA32(a, b, c)    __builtin_amdgcn_mfma_f32_32x32x16_bf16((a), (b), (c), 0, 0, 0)
#define LO4(v) __builtin_shufflevector((v), (v), 0, 1, 2, 3)
#define HI4(v) __builtin_shufflevector((v), (v), 4, 5, 6, 7)

#define GLOAD16(g, l)                                                        \
  __builtin_amdgcn_global_load_lds(                                          \
      (__attribute__((address_space(1))) void*)(g),                          \
      (__attribute__((address_space(3))) void*)(l), 16, 0, 0)

__device__ __forceinline__ unsigned short f2bf(float f) {
  union { float f; u32 u; } x; x.f = f;
  u32 r = (x.u + 0x7fffu + ((x.u >> 16) & 1u)) >> 16;
  return (unsigned short)r;
}

static __device__ __forceinline__ u32 cvtpk1(float a, float b) {
  u32 r;
  asm("v_cvt_pk_bf16_f32 %0, %1, %2" : "=v"(r) : "v"(a), "v"(b));
  return r;
}
static __device__ __forceinline__ void pl32swap(u32& a, u32& b) {
  asm("v_permlane32_swap_b32 %0, %1" : "+v"(a), "+v"(b));
}

// ---------------- kernel 1: x fp32 -> bf16 ----------------
__global__ void cvt_x_kernel(const float* __restrict__ x, unsigned short* __restrict__ xb) {
  int i = blockIdx.x * 256 + threadIdx.x;
  float4 v = ((const float4*)x)[i];
  ushort4 o;
  o.x = f2bf(v.x); o.y = f2bf(v.y); o.z = f2bf(v.z); o.w = f2bf(v.w);
  ((ushort4*)xb)[i] = o;
}

// ---------------- kernel 2: w [1024][3072] fp32 -> wT [3072][1024] bf16 ----
__global__ void transpose_w_kernel(const float* __restrict__ w, unsigned short* __restrict__ wT) {
  __shared__ unsigned short TL[64][72];
  const int tid = threadIdx.x;
  const int c0 = blockIdx.x * 64;
  const int r0 = blockIdx.y * 64;
#pragma unroll
  for (int p = 0; p < 4; ++p) {
    int r = p * 16 + (tid >> 4);
    int c = (tid & 15) * 4;
    float4 v = *(const float4*)&w[(size_t)(r0 + r) * 3072 + c0 + c];
    TL[c + 0][r] = f2bf(v.x);
    TL[c + 1][r] = f2bf(v.y);
    TL[c + 2][r] = f2bf(v.z);
    TL[c + 3][r] = f2bf(v.w);
  }
  __syncthreads();
#pragma unroll
  for (int p = 0; p < 4; ++p) {
    int c = p * 16 + (tid >> 4);
    int r = (tid & 15) * 4;
    ushort4 o;
    o.x = TL[c][r + 0]; o.y = TL[c][r + 1]; o.z = TL[c][r + 2]; o.w = TL[c][r + 3];
    *(ushort4*)&wT[(size_t)(c0 + c) * 1024 + r0 + r] = o;
  }
}

// ---------------- kernel 3: GEMM qkv = xb @ wT^T + bias ------------------
// bn<8:  q (1/8-scaled) -> Qrm [4096][1024] row-major
// bn<16: k -> Kf frag-order directly (TL untransposed, 2 t-half passes)
// else:  v -> Vf frag-order (TL transposed, 2 head passes)
// Kf frag(bh,c,m): elem l*8+e = K[s=c*32+(l&31)][d=m*16+(l>>5)*8+e]
// Vf frag(bh,c,sb,dh): elem l*8+e = V[s=c*32+sb*16+(l>>5)*8+e][d=dh*32+(l&31)]
__global__ __launch_bounds__(256, 3) void gemm_qkv_kernel(
    const unsigned short* __restrict__ A, const unsigned short* __restrict__ Bt,
    const float* __restrict__ bias, unsigned short* __restrict__ Qrm,
    unsigned short* __restrict__ Kf, unsigned short* __restrict__ Vf) {
  __shared__ __align__(16) unsigned short SM[8448];   // As | Bs, reused as TL
  unsigned short* As = SM;
  unsigned short* Bs = SM + 4096;
  const int tid = threadIdx.x;
  const int lane = tid & 63, wid = tid >> 6;
  const int wr = wid >> 1, wc = wid & 1;
  const int g = lane >> 4, lm = lane & 15;
  const int bid = blockIdx.x;
  const int xcd = bid & 7, wl = bid >> 3;              // wl 0..95
  const int bn = wl % 24;
  const int bm = xcd * 4 + wl / 24;

  const unsigned short* gA = A  + (size_t)(bm * 128 + wid * 32 + (lane >> 2)) * 1024 + (lane & 3) * 8;
  const unsigned short* gB = Bt + (size_t)(bn * 128 + wid * 32 + (lane >> 2)) * 1024 + (lane & 3) * 8;
  unsigned short* lA0 = &As[wid * 1024];
  unsigned short* lA1 = &As[wid * 1024 + 512];
  unsigned short* lB0 = &Bs[wid * 1024];
  unsigned short* lB1 = &Bs[wid * 1024 + 512];

  f32x4 acc[4][4] = {};

  for (int kt = 0; kt < 32; ++kt) {
    __syncthreads();
    const unsigned short* a0 = gA + kt * 32;
    const unsigned short* b0 = gB + kt * 32;
    GLOAD16(a0,             lA0);
    GLOAD16(a0 + 16 * 1024, lA1);
    GLOAD16(b0,             lB0);
    GLOAD16(b0 + 16 * 1024, lB1);
    __syncthreads();

    s16x8 af[4], bf[4];
#pragma unroll
    for (int m = 0; m < 4; ++m)
      af[m] = *(const s16x8*)&As[(wr * 64 + m * 16 + lm) * 32 + g * 8];
#pragma unroll
    for (int n = 0; n < 4; ++n)
      bf[n] = *(const s16x8*)&Bs[(wc * 64 + n * 16 + lm) * 32 + g * 8];
#pragma unroll
    for (int m = 0; m < 4; ++m)
#pragma unroll
      for (int n = 0; n < 4; ++n)
        acc[m][n] = MFMA_BF16(af[m], bf[n], acc[m][n]);
  }

  const int bb = bm >> 4;                        // batch
  if (bn < 8) {                                  // q, pre-scaled by 1/8
#pragma unroll
    for (int m = 0; m < 4; ++m) {
      const int row = bm * 128 + wr * 64 + m * 16 + g * 4;
#pragma unroll
      for (int n = 0; n < 4; ++n) {
        const int col = bn * 128 + wc * 64 + n * 16 + lm;
        const float bv = bias[col];
#pragma unroll
        for (int r = 0; r < 4; ++r)
          Qrm[(size_t)(row + r) * 1024 + col] = f2bf((acc[m][n][r] + bv) * 0.125f);
      }
    }
  } else if (bn < 16) {                          // k -> Kf frag-order via TL
    unsigned short* TL = SM;                     // [64 t][132] (128 cols + pad)
    __syncthreads();                             // As/Bs reads done
#pragma unroll
    for (int p = 0; p < 2; ++p) {                // t-half
      if (wr == p) {
#pragma unroll
        for (int m = 0; m < 4; ++m) {
#pragma unroll
          for (int n = 0; n < 4; ++n) {
            const int col = wc * 64 + n * 16 + lm;          // 0..127 (2 heads)
            const float bv = bias[1024 + (bn - 8) * 128 + col];
#pragma unroll
            for (int r = 0; r < 4; ++r)
              TL[(m * 16 + g * 4 + r) * 132 + col] = f2bf(acc[m][n][r] + bv);
          }
        }
      }
      __syncthreads();
      const int li2 = lane & 31, hiL2 = lane >> 5;
#pragma unroll
      for (int f = 0; f < 4; ++f) {
        const int frag = f * 4 + wid;            // 0..15
        const int c_loc = frag >> 3, head = (frag >> 2) & 1, m = frag & 3;
        const int hg = (bn - 8) * 2 + head;
        const int c = (bm & 15) * 4 + p * 2 + c_loc;
        s16x8 o = *(const s16x8*)&TL[(c_loc * 32 + li2) * 132 + head * 64 + m * 16 + hiL2 * 8];
        *(s16x8*)&Kf[(((size_t)(bb * 16 + hg) * 64 + c) * 4 + m) * 512 + lane * 8] = o;
      }
      __syncthreads();
    }
  } else {                                       // v -> Vf frag-order via TL
    unsigned short* TL = SM;                     // [64 d][132 t-pad]
    const int bmt = bm & 15;                     // t-block
    __syncthreads();                             // As/Bs reads done
#pragma unroll
    for (int p = 0; p < 2; ++p) {
      const int h = (bn - 16) * 2 + p;           // this pass's head
      const size_t fb = (size_t)(bb * 16 + h) * 64 * 4;   // frag base
      if (wc == p) {
#pragma unroll
        for (int m = 0; m < 4; ++m) {
          const int r = wr * 64 + m * 16 + g * 4;
#pragma unroll
          for (int n = 0; n < 4; ++n) {
            const int c = n * 16 + lm;           // d 0..63
            const float bv = bias[2048 + h * 64 + c];
            ushort4 o;
#pragma unroll
            for (int r2 = 0; r2 < 4; ++r2)
              ((unsigned short*)&o)[r2] = f2bf(acc[m][n][r2] + bv);
            *(ushort4*)&TL[c * 132 + r] = o;
          }
        }
      }
      __syncthreads();
      const int li = tid & 31, grp = tid >> 5;
      const int dh = grp & 1, oct8 = grp >> 1;
      const int cl = dh * 32 + li;               // d
#pragma unroll
      for (int k2 = 0; k2 < 4; ++k2) {
        const int oct = oct8 * 4 + k2;           // t-octet 0..15
        const int c = bmt * 4 + (oct >> 2);
        const int sb = (oct >> 1) & 1, hiL2 = oct & 1;
        union { s16x8 v; s16x4 hv[2]; } o;
        o.hv[0] = *(const s16x4*)&TL[cl * 132 + oct * 8];
        o.hv[1] = *(const s16x4*)&TL[cl * 132 + oct * 8 + 4];
        *(s16x8*)&Vf[(fb + (size_t)c * 4 + sb * 2 + dh) * 512 + (hiL2 * 32 + li) * 8] = o.v;
      }
      __syncthreads();
    }
  }
}

// ---------------- kernel 4: attention v11 (v10 + counted-vmcnt pipeline) --
// 512 blocks (2/CU) x 4 warps; block owns 64-row tiles (31-j, j): 33 steps.
// Warp (wt, half): 32 q-rows x s-half. Triple-buffered LDS; STAGE for step
// u+2 issued at end of step u (4 gload_lds/wave). Step top: s_waitcnt
// vmcnt(4) (oldest 4 = this step's loads) + raw s_barrier + sched_barrier —
// loads for u+1/u+2 stay in flight across the barrier (T3/T4). T15 deferred
// PV; tile-end steps use full __syncthreads (merge/store, 2 of 33).
__global__ __launch_bounds__(256, 2) void attn_kernel(
    const unsigned short* __restrict__ Qrm, const unsigned short* __restrict__ Kf,
    const unsigned short* __restrict__ Vf, float* __restrict__ out) {
  __shared__ __align__(16) unsigned short Ks[3][4096];
  __shared__ __align__(16) unsigned short Vs[3][4096];
  const int tid = threadIdx.x, lane = tid & 63, w = tid >> 6;   // w 0..3
  const int hiL = lane >> 5, li = lane & 31;
  const int wt = w >> 1, half = w & 1;
  const int bid = blockIdx.x;
  const int xcd = bid & 7, rest = bid >> 3;      // rest 0..63
  const int bh = xcd * 4 + (rest >> 4);          // XCD-pinned (b,h)
  const int j = rest & 15;
  const int b = bh >> 4, h = bh & 15;
  const int thi = 31 - j, tlo = j;               // 64-row tiles (thi >= 16)
  const unsigned short* Kb = Kf + (size_t)bh * 64 * 2048;
  const unsigned short* Vb = Vf + (size_t)bh * 64 * 2048;
  const size_t qstr = (size_t)(b * 2048) * 1024 + h * 64 + hiL * 8;

#define STAGE(buf, stx)                                                      \
  do {                                                                       \
    const unsigned short* kk = Kb + (size_t)(stx) * 8 * 512 + lane * 8;      \
    const unsigned short* vv = Vb + (size_t)(stx) * 8 * 512 + lane * 8;      \
    if (w < 2) {                                                             \
      _Pragma("unroll")                                                      \
      for (int f = 0; f < 4; ++f)                                            \
        GLOAD16(kk + (w * 4 + f) * 512, &Ks[buf][(w * 4 + f) * 512]);        \
    } else {                                                                 \
      _Pragma("unroll")                                                      \
      for (int f = 0; f < 4; ++f)                                            \
        GLOAD16(vv + ((w - 2) * 4 + f) * 512, &Vs[buf][((w - 2) * 4 + f) * 512]); \
    }                                                                        \
  } while (0)

// SM: pr[] -> pa0s, pa1s
#define PACK_PA()                                                            \
  do {                                                                       \
    u32 a0 = cvtpk1(pr[0], pr[1]);                                           \
    u32 b0 = cvtpk1(pr[4], pr[5]);                                           \
    u32 a1 = cvtpk1(pr[2], pr[3]);                                           \
    u32 b1 = cvtpk1(pr[6], pr[7]);                                           \
    pl32swap(a0, b0); pl32swap(a1, b1);                                      \
    union { s16x8 v; u32 wv[4]; } pk0;                                       \
    pk0.wv[0] = a0; pk0.wv[1] = a1; pk0.wv[2] = b0; pk0.wv[3] = b1;          \
    pa0s = pk0.v;                                                            \
    u32 c0 = cvtpk1(pr[8], pr[9]);                                           \
    u32 d0 = cvtpk1(pr[12], pr[13]);                                         \
    u32 c1 = cvtpk1(pr[10], pr[11]);                                         \
    u32 d1 = cvtpk1(pr[14], pr[15]);                                         \
    pl32swap(c0, d0); pl32swap(c1, d1);                                      \
    union { s16x8 v; u32 wv[4]; } pk1;                                       \
    pk1.wv[0] = c0; pk1.wv[1] = c1; pk1.wv[2] = d0; pk1.wv[3] = d1;          \
    pa1s = pk1.v;                                                            \
  } while (0)

  int qrow0 = thi * 64 + wt * 32;
  s16x8 qf0, qf1, qf2, qf3;
  {
    const unsigned short* qp = &Qrm[qstr + (size_t)(qrow0 + li) * 1024];
    qf0 = *(const s16x8*)(qp);      qf1 = *(const s16x8*)(qp + 16);
    qf2 = *(const s16x8*)(qp + 32); qf3 = *(const s16x8*)(qp + 48);
  }
  f32x16 y0 = {}, y1 = {};
  s16x8 pa0s = {}, pa1s = {}, vv0 = {}, vv1 = {}, vv2 = {}, vv3 = {};
  bool have_prev = false;

  STAGE(0, 0);                                   // steps 0,1 (both in tile thi)
  STAGE(1, 1);

  for (int u = 0; u < 33; ++u) {
    const int tl = (u <= thi) ? thi : tlo;
    const int st = (u <= thi) ? u : (u - thi - 1);
    const int bsel = u % 3;
    asm volatile("s_waitcnt vmcnt(4)" ::: "memory");   // oldest 4 = buf[bsel]
    __builtin_amdgcn_s_barrier();
    __builtin_amdgcn_sched_barrier(0);
    const unsigned short* Kc = &Ks[bsel][half * 2048];
    const unsigned short* Vc = &Vs[bsel][half * 2048];

    __builtin_amdgcn_s_setprio(1);
    if (have_prev) {                             // PV(u-1): indep MFMA burst
      y0 = MFMA32(pa0s, vv0, y0);
      y1 = MFMA32(pa0s, vv1, y1);
      y0 = MFMA32(pa1s, vv2, y0);
      y1 = MFMA32(pa1s, vv3, y1);
    }
    if (st < tl) {                               // full step: defer PV
      f32x16 sa = {}, sb = {};
      sa = MFMA32(*(const s16x8*)(Kc + 0 * 512 + lane * 8), qf0, sa);
      sa = MFMA32(*(const s16x8*)(Kc + 1 * 512 + lane * 8), qf1, sa);
      sb = MFMA32(*(const s16x8*)(Kc + 2 * 512 + lane * 8), qf2, sb);
      sb = MFMA32(*(const s16x8*)(Kc + 3 * 512 + lane * 8), qf3, sb);
      vv0 = *(const s16x8*)(Vc + 0 * 512 + lane * 8);
      vv1 = *(const s16x8*)(Vc + 1 * 512 + lane * 8);
      vv2 = *(const s16x8*)(Vc + 2 * 512 + lane * 8);
      vv3 = *(const s16x8*)(Vc + 3 * 512 + lane * 8);
      __builtin_amdgcn_s_setprio(0);
      float pr[16];
#pragma unroll
      for (int r = 0; r < 16; ++r) {
        const float v = sa[r] + sb[r];
        pr[r] = v > 0.f ? v : 0.f;
      }
      PACK_PA();
      have_prev = true;
    } else {                                     // tile-end step
      if (half <= wt) {                          // causally active
        f32x16 sa = {}, sb = {};
        sa = MFMA32(*(const s16x8*)(Kc + 0 * 512 + lane * 8), qf0, sa);
        sa = MFMA32(*(const s16x8*)(Kc + 1 * 512 + lane * 8), qf1, sa);
        sb = MFMA32(*(const s16x8*)(Kc + 2 * 512 + lane * 8), qf2, sb);
        sb = MFMA32(*(const s16x8*)(Kc + 3 * 512 + lane * 8), qf3, sb);
        vv0 = *(const s16x8*)(Vc + 0 * 512 + lane * 8);
        vv1 = *(const s16x8*)(Vc + 1 * 512 + lane * 8);
        vv2 = *(const s16x8*)(Vc + 2 * 512 + lane * 8);
        vv3 = *(const s16x8*)(Vc + 3 * 512 + lane * 8);
        const int sEff = st * 64 + half * 32;
        float pr[16];
#pragma unroll
        for (int r = 0; r < 16; ++r) {
          float v = sa[r] + sb[r];
          v = v > 0.f ? v : 0.f;
          if (half == wt) {                      // diagonal mask
            const int sg = sEff + (r & 3) + 8 * (r >> 2) + 4 * hiL;
            if (sg > qrow0 + li) v = 0.f;
          }
          pr[r] = v;
        }
        PACK_PA();
        y0 = MFMA32(pa0s, vv0, y0);              // PV immediate (pre-flush)
        y1 = MFMA32(pa0s, vv1, y1);
        y0 = MFMA32(pa1s, vv2, y0);
        y1 = MFMA32(pa1s, vv3, y1);
      }
      __builtin_amdgcn_s_setprio(0);
      have_prev = false;
      // merge s-halves via consumed LDS buffer, store
      __syncthreads();                           // full drain (2x per kernel)
      float* M = wt ? (float*)&Vs[bsel][0] : (float*)&Ks[bsel][0];
      if (half == 0) {
#pragma unroll
        for (int r = 0; r < 16; ++r) {
          const int ql = (r & 3) + 8 * (r >> 2) + 4 * hiL;
          M[ql * 64 + li]      = y0[r];
          M[ql * 64 + li + 32] = y1[r];
        }
      }
      __syncthreads();
      if (half == 1) {
        const size_t ob = (size_t)(b * 2048 + qrow0) * 1024 + h * 64 + li;
#pragma unroll
        for (int r = 0; r < 16; ++r) {
          const int ql = (r & 3) + 8 * (r >> 2) + 4 * hiL;
          out[ob + (size_t)ql * 1024]      = y0[r] + M[ql * 64 + li];
          out[ob + (size_t)ql * 1024 + 32] = y1[r] + M[ql * 64 + li + 32];
        }
      }
      if (u < 32) {                              // switch to tile tlo
        qrow0 = tlo * 64 + wt * 32;
        const unsigned short* qp = &Qrm[qstr + (size_t)(qrow0 + li) * 1024];
        qf0 = *(const s16x8*)(qp);      qf1 = *(const s16x8*)(qp + 16);
        qf2 = *(const s16x8*)(qp + 32); qf3 = *(const s16x8*)(qp + 48);
        y0 = (f32x16){}; y1 = (f32x16){};
      }
    }
    if (u + 2 < 33) {                            // issue stage for step u+2
      const int un = u + 2;
      const int stn = (un <= thi) ? un : (un - thi - 1);
      STAGE(un % 3, stn);
    }
  }
#undef STAGE
#undef PACK_PA
}

extern "C" void kernel_launch(void* const* d_in, const int* in_sizes, int n_in,
                              void* d_out, int out_size, void* d_ws, size_t ws_size,
                              hipStream_t stream) {
  const float* x    = (const float*)d_in[0];
  const float* w    = (const float*)d_in[1];
  const float* bias = (const float*)d_in[2];
  float* out = (float*)d_out;

  unsigned short* xb  = (unsigned short*)d_ws;            // 4096*1024
  unsigned short* wT  = xb  + (size_t)4096 * 1024;        // 3072*1024
  unsigned short* Qrm = wT  + (size_t)3072 * 1024;        // 4096*1024
  unsigned short* Kf  = Qrm + (size_t)4096 * 1024;        // 4096*1024 (frag-order)
  unsigned short* Vf  = Kf  + (size_t)4096 * 1024;        // 4096*1024 (frag-order)

  cvt_x_kernel<<<4096, 256, 0, stream>>>(x, xb);
  transpose_w_kernel<<<dim3(48, 16), 256, 0, stream>>>(w, wT);
  gemm_qkv_kernel<<<768, 256, 0, stream>>>(xb, wT, bias, Qrm, Kf, Vf);
  attn_kernel<<<512, 256, 0, stream>>>(Qrm, Kf, Vf, out);
}